// Round 3
// baseline (10762.136 us; speedup 1.0000x reference)
//
#include <hip/hip_runtime.h>
#include <hip/hip_bf16.h>
#include <math.h>

#define BB 256
#define TT 64
#define UU 512

typedef __hip_bfloat16 bf16;
typedef __attribute__((ext_vector_type(8))) short sh8;     // 8 x bf16 = 4 VGPRs
typedef __attribute__((ext_vector_type(4))) short sh4;     // 4 x bf16 = 8B
typedef __attribute__((ext_vector_type(4))) float floatx4; // MFMA acc

__device__ __forceinline__ float bf2f(short s) {
    union { unsigned int u; float f; } v;
    v.u = ((unsigned int)(unsigned short)s) << 16;
    return v.f;
}
__device__ __forceinline__ short f2bf(float f) {
    union { float f; unsigned int u; } v; v.f = f;
    unsigned int r = v.u + 0x7fff + ((v.u >> 16) & 1);   // RNE
    return (short)(r >> 16);
}
__device__ __forceinline__ float fsig(float x)  { return 1.0f / (1.0f + __expf(-x)); }
__device__ __forceinline__ float ftanh(float x) { return 2.0f / (1.0f + __expf(-2.0f * x)) - 1.0f; }

// ---------------- transpose + fp32->bf16 convert ----------------
// in: [K x N] fp32 row-major. out[n * out_stride + k] = bf16(in[k][n]).
// grid (N/32, K/32), block 256.
__global__ void transpose_conv_kernel(const float* __restrict__ in, bf16* __restrict__ out,
                                      int K, int N, int out_stride) {
    __shared__ float tile[32][33];
    int k0 = blockIdx.y * 32;
    int n0 = blockIdx.x * 32;
    int tid = threadIdx.x;
    int nn = tid & 31, kk = tid >> 5;
    #pragma unroll
    for (int j = 0; j < 4; ++j)
        tile[kk + j * 8][nn] = in[(size_t)(k0 + kk + j * 8) * N + n0 + nn];
    __syncthreads();
    int kk2 = tid & 31, nn2 = tid >> 5;
    #pragma unroll
    for (int j = 0; j < 4; ++j)
        out[(size_t)(n0 + nn2 + j * 8) * out_stride + k0 + kk2] =
            __float2bfloat16(tile[kk2][nn2 + j * 8]);
}

// ---------------- mean-pool over 10x10 spatial ----------------
__global__ void pool_kernel(const float* __restrict__ enc, float* __restrict__ pooled) {
    int b = blockIdx.y;
    int e = blockIdx.x * 256 + threadIdx.x;
    const float* p = enc + (size_t)b * 100 * 2048 + e;
    float s = 0.f;
    #pragma unroll 4
    for (int i = 0; i < 100; ++i) s += p[(size_t)i * 2048];
    pooled[(size_t)b * 2048 + e] = s * 0.01f;
}

// ---------------- embedding gather -> bf16 ----------------
__global__ void embed_kernel(const int* __restrict__ seq, const float* __restrict__ emb,
                             bf16* __restrict__ tok) {
    int i = blockIdx.x;
    int e = threadIdx.x;
    tok[(size_t)i * 256 + e] = __float2bfloat16(emb[(size_t)seq[i] * 256 + e]);
}

// ---------------- dense MFMA: out = act(A @ Wt^T + b) ----------------
// A: [M x K] bf16 row-major. Wt: [N x K] bf16. bias fp32.
// Block tile 128(M) x 64(N), 4 waves; wave = 64x32 (4x2 MFMA frags, 8 MFMA / 6 loads per kc).
// btperm: write out[((m&63)*256 + (m>>6)) * N + col]  (i.e. [t][b][N] for m = b*64+t)
__global__ __launch_bounds__(256)
void dense_mfma(const bf16* __restrict__ A, const bf16* __restrict__ Wt,
                const float* __restrict__ bias, bf16* __restrict__ out,
                int M, int N, int K, int relu, int btperm) {
    const int tid = threadIdx.x;
    const int w = tid >> 6, lane = tid & 63;
    const int lm = lane & 15, q = lane >> 4;
    const int r0 = blockIdx.y * 128 + (w & 1) * 64;
    const int c0 = blockIdx.x * 64 + (w >> 1) * 32;

    floatx4 acc[4][2];
    #pragma unroll
    for (int i = 0; i < 4; ++i)
        #pragma unroll
        for (int j = 0; j < 2; ++j) acc[i][j] = (floatx4){0.f, 0.f, 0.f, 0.f};

    const bf16* ar[4];
    const bf16* wr[2];
    #pragma unroll
    for (int i = 0; i < 4; ++i) ar[i] = A + (size_t)(r0 + i * 16 + lm) * K + q * 8;
    #pragma unroll
    for (int j = 0; j < 2; ++j) wr[j] = Wt + (size_t)(c0 + j * 16 + lm) * K + q * 8;

    for (int k0 = 0; k0 < K; k0 += 32) {
        sh8 a0 = *(const sh8*)(ar[0] + k0);
        sh8 a1 = *(const sh8*)(ar[1] + k0);
        sh8 a2 = *(const sh8*)(ar[2] + k0);
        sh8 a3 = *(const sh8*)(ar[3] + k0);
        sh8 b0 = *(const sh8*)(wr[0] + k0);
        sh8 b1 = *(const sh8*)(wr[1] + k0);
        acc[0][0] = __builtin_amdgcn_mfma_f32_16x16x32_bf16(a0, b0, acc[0][0], 0, 0, 0);
        acc[0][1] = __builtin_amdgcn_mfma_f32_16x16x32_bf16(a0, b1, acc[0][1], 0, 0, 0);
        acc[1][0] = __builtin_amdgcn_mfma_f32_16x16x32_bf16(a1, b0, acc[1][0], 0, 0, 0);
        acc[1][1] = __builtin_amdgcn_mfma_f32_16x16x32_bf16(a1, b1, acc[1][1], 0, 0, 0);
        acc[2][0] = __builtin_amdgcn_mfma_f32_16x16x32_bf16(a2, b0, acc[2][0], 0, 0, 0);
        acc[2][1] = __builtin_amdgcn_mfma_f32_16x16x32_bf16(a2, b1, acc[2][1], 0, 0, 0);
        acc[3][0] = __builtin_amdgcn_mfma_f32_16x16x32_bf16(a3, b0, acc[3][0], 0, 0, 0);
        acc[3][1] = __builtin_amdgcn_mfma_f32_16x16x32_bf16(a3, b1, acc[3][1], 0, 0, 0);
    }

    #pragma unroll
    for (int i = 0; i < 4; ++i)
        #pragma unroll
        for (int j = 0; j < 2; ++j) {
            int col = c0 + j * 16 + lm;
            float bv = bias[col];
            #pragma unroll
            for (int r = 0; r < 4; ++r) {
                int m = r0 + i * 16 + q * 4 + r;
                float v = acc[i][j][r] + bv;
                if (relu) v = fmaxf(v, 0.f);
                size_t oaddr = btperm ? ((size_t)(m & 63) * 256 + (m >> 6)) * N + col
                                      : (size_t)m * N + col;
                out[oaddr] = __float2bfloat16(v);
            }
        }
}

// ---------------- persistent BiLSTM layer: all 64 steps in one launch ----------------
// 32 blocks x 256 threads. dir = bx&1 (XCD-parity heuristic), batch tile = 16 rows.
// Block owns batch rows [rb, rb+16) x ALL 2048 gate-cols -> recurrence is block-local.
// h lives in LDS (double-buffered, padded rows); c and h carried in registers.
// MFMA roles: A = Wh rows (n-dim), B = h rows (batch) => D: row = n, col = batch.
// Wave w owns u-slice [w*128, (w+1)*128) for all 4 gates (epilogue fully in-lane).
// xw: [dir][t][b][2048] bf16, bias pre-added (acc init). Wht: [dir][2048][512] bf16.
__global__ __launch_bounds__(256, 1)
void lstm_layer_kernel(const bf16* __restrict__ xw, const bf16* __restrict__ Wht,
                       const int* __restrict__ seq,
                       bf16* __restrict__ seqout,   // [b][t][dir*512+u] or null
                       bf16* __restrict__ hfinal) { // [dir][b][u] or null
    const int bx = blockIdx.x;
    const int dir = bx & 1;
    const int rb = (bx >> 1) * 16;
    const int tid = threadIdx.x;
    const int w = tid >> 6, lane = tid & 63;
    const int lm = lane & 15;      // batch (B-frag col / D col)
    const int q = lane >> 4;       // k-octet / D row-quad

    __shared__ short hbuf[2][16][520];   // row stride 520 (bank-shift 4/row)

    // zero read-buffer for step 0
    for (int i = tid; i < 16 * 520; i += 256) ((short*)hbuf)[i] = 0;

    const bf16* Wd = Wht + (size_t)dir * 2048 * 512;
    const int b_row = rb + lm;

    // per-lane weight offsets (elements), fixed across steps
    int woff[4][8];
    #pragma unroll
    for (int g = 0; g < 4; ++g)
        #pragma unroll
        for (int uf = 0; uf < 8; ++uf)
            woff[g][uf] = (g * 512 + w * 128 + uf * 16 + lm) * 512 + q * 8;

    floatx4 c_[8], h_[8];
    #pragma unroll
    for (int uf = 0; uf < 8; ++uf) {
        c_[uf] = (floatx4){0.f, 0.f, 0.f, 0.f};
        h_[uf] = (floatx4){0.f, 0.f, 0.f, 0.f};
    }

    __syncthreads();

    for (int s = 0; s < TT; ++s) {
        const int t = dir ? (TT - 1 - s) : s;
        const int cur = s & 1, nxt = cur ^ 1;

        // acc init = xw (bias pre-added) in C/D layout: row n = g*512+w*128+uf*16+q*4+r, col b=lm
        const bf16* xwrow = xw + (((size_t)(dir * TT + t) * BB) + b_row) * 2048
                               + w * 128 + q * 4;
        floatx4 acc[4][8];
        #pragma unroll
        for (int g = 0; g < 4; ++g)
            #pragma unroll
            for (int uf = 0; uf < 8; ++uf) {
                sh4 xv = *(const sh4*)(xwrow + g * 512 + uf * 16);
                acc[g][uf] = (floatx4){bf2f(xv[0]), bf2f(xv[1]), bf2f(xv[2]), bf2f(xv[3])};
            }

        // z += h @ Wh : 16 k-chunks x (4 gates x 8 u-frags)
        #pragma unroll 2
        for (int kc = 0; kc < 16; ++kc) {
            sh8 hb = *(const sh8*)&hbuf[cur][lm][kc * 32 + q * 8];
            #pragma unroll
            for (int g = 0; g < 4; ++g)
                #pragma unroll
                for (int uf = 0; uf < 8; ++uf) {
                    sh8 a = *(const sh8*)(Wd + woff[g][uf] + kc * 32);
                    acc[g][uf] = __builtin_amdgcn_mfma_f32_16x16x32_bf16(a, hb, acc[g][uf], 0, 0, 0);
                }
        }

        // epilogue: gates i,f,g,o; masked carry; h -> LDS (+seqout)
        const bool msk = (seq[b_row * TT + t] != 0);
        #pragma unroll
        for (int uf = 0; uf < 8; ++uf) {
            #pragma unroll
            for (int r = 0; r < 4; ++r) {
                float ig = fsig(acc[0][uf][r]);
                float fg = fsig(acc[1][uf][r]);
                float gg = ftanh(acc[2][uf][r]);
                float og = fsig(acc[3][uf][r]);
                float cn = fg * c_[uf][r] + ig * gg;
                float hn = og * ftanh(cn);
                if (msk) { c_[uf][r] = cn; h_[uf][r] = hn; }
            }
            int u = w * 128 + uf * 16 + q * 4;
            sh4 hw;
            hw[0] = f2bf(h_[uf][0]); hw[1] = f2bf(h_[uf][1]);
            hw[2] = f2bf(h_[uf][2]); hw[3] = f2bf(h_[uf][3]);
            *(sh4*)&hbuf[nxt][lm][u] = hw;
            if (seqout)
                *(sh4*)&seqout[((size_t)b_row * TT + t) * 1024 + dir * 512 + u] = hw;
        }
        __syncthreads();
    }

    if (hfinal) {
        #pragma unroll
        for (int uf = 0; uf < 8; ++uf) {
            int u = w * 128 + uf * 16 + q * 4;
            sh4 hw;
            hw[0] = f2bf(h_[uf][0]); hw[1] = f2bf(h_[uf][1]);
            hw[2] = f2bf(h_[uf][2]); hw[3] = f2bf(h_[uf][3]);
            *(sh4*)&hfinal[((size_t)dir * BB + b_row) * UU + u] = hw;
        }
    }
}

// ---------------- feats = [pooled | h2f | h2b] (bf16) ----------------
__global__ void concat_kernel(const float* __restrict__ pooled, const bf16* __restrict__ h2,
                              bf16* __restrict__ feats) {
    int b = blockIdx.x;
    for (int j = threadIdx.x; j < 3072; j += 256) {
        bf16 v;
        if (j < 2048) v = __float2bfloat16(pooled[(size_t)b * 2048 + j]);
        else {
            int u = j - 2048;
            int dir = u >> 9;
            int uu = u & 511;
            v = h2[((size_t)dir * BB + b) * UU + uu];
        }
        feats[(size_t)b * 3072 + j] = v;
    }
}

// ---------------- out = sigmoid(x2 @ W3 + b3), K=512 ----------------
__global__ void final_kernel(const bf16* __restrict__ x2, const float* __restrict__ W3,
                             const float* __restrict__ b3, float* __restrict__ out) {
    int b = blockIdx.x;
    int tid = threadIdx.x;
    float v = __bfloat162float(x2[(size_t)b * 512 + tid]) * W3[tid]
            + __bfloat162float(x2[(size_t)b * 512 + 256 + tid]) * W3[256 + tid];
    for (int off = 32; off > 0; off >>= 1) v += __shfl_down(v, off, 64);
    __shared__ float wsum[4];
    if ((tid & 63) == 0) wsum[tid >> 6] = v;
    __syncthreads();
    if (tid == 0) {
        float s = wsum[0] + wsum[1] + wsum[2] + wsum[3] + b3[0];
        out[b] = 1.0f / (1.0f + expf(-s));
    }
}

extern "C" void kernel_launch(void* const* d_in, const int* in_sizes, int n_in,
                              void* d_out, int out_size, void* d_ws, size_t ws_size,
                              hipStream_t stream) {
    const float* enc    = (const float*)d_in[0];
    const int*   seq    = (const int*)  d_in[1];
    const float* emb    = (const float*)d_in[2];
    const float* l1f_Wi = (const float*)d_in[3];
    const float* l1f_Wh = (const float*)d_in[4];
    const float* l1f_b  = (const float*)d_in[5];
    const float* l1b_Wi = (const float*)d_in[6];
    const float* l1b_Wh = (const float*)d_in[7];
    const float* l1b_b  = (const float*)d_in[8];
    const float* l2f_Wi = (const float*)d_in[9];
    const float* l2f_Wh = (const float*)d_in[10];
    const float* l2f_b  = (const float*)d_in[11];
    const float* l2b_Wi = (const float*)d_in[12];
    const float* l2b_Wh = (const float*)d_in[13];
    const float* l2b_b  = (const float*)d_in[14];
    const float* W1     = (const float*)d_in[15];
    const float* b1     = (const float*)d_in[16];
    const float* W2     = (const float*)d_in[17];
    const float* b2     = (const float*)d_in[18];
    const float* W3     = (const float*)d_in[19];
    const float* b3     = (const float*)d_in[20];

    // ---- workspace layout, ~207 MB (ws ~839 MB) ----
    char* p = (char*)d_ws;
    bf16* tok      = (bf16*)p;  p += (size_t)BB * TT * 256 * 2;
    bf16* lstm1out = (bf16*)p;  p += (size_t)BB * TT * 1024 * 2;
    bf16* xw       = (bf16*)p;  p += (size_t)2 * TT * BB * 2048 * 2;   // [dir][t][b][2048]
    bf16* Wh1t     = (bf16*)p;  p += (size_t)2 * 2048 * 512 * 2;
    bf16* Wh2t     = (bf16*)p;  p += (size_t)2 * 2048 * 512 * 2;
    bf16* Wi1t     = (bf16*)p;  p += (size_t)2 * 2048 * 256 * 2;
    bf16* Wi2t     = (bf16*)p;  p += (size_t)2 * 2048 * 1024 * 2;
    bf16* W1t      = (bf16*)p;  p += (size_t)1024 * 3072 * 2;
    bf16* W2t      = (bf16*)p;  p += (size_t)512 * 1024 * 2;
    float* pooled  = (float*)p; p += (size_t)BB * 2048 * 4;
    bf16* feats    = (bf16*)p;  p += (size_t)BB * 3072 * 2;
    bf16* x1       = (bf16*)p;  p += (size_t)BB * 1024 * 2;
    bf16* x2       = (bf16*)p;  p += (size_t)BB * 512 * 2;
    bf16* h2final  = (bf16*)p;  p += (size_t)2 * BB * UU * 2;

    // ---- weight transposes (one-time per call) ----
    transpose_conv_kernel<<<dim3(64, 16), 256, 0, stream>>>(l1f_Wh, Wh1t,                   512, 2048, 512);
    transpose_conv_kernel<<<dim3(64, 16), 256, 0, stream>>>(l1b_Wh, Wh1t + (size_t)2048*512, 512, 2048, 512);
    transpose_conv_kernel<<<dim3(64, 16), 256, 0, stream>>>(l2f_Wh, Wh2t,                   512, 2048, 512);
    transpose_conv_kernel<<<dim3(64, 16), 256, 0, stream>>>(l2b_Wh, Wh2t + (size_t)2048*512, 512, 2048, 512);
    transpose_conv_kernel<<<dim3(64, 8),  256, 0, stream>>>(l1f_Wi, Wi1t,                    256, 2048, 256);
    transpose_conv_kernel<<<dim3(64, 8),  256, 0, stream>>>(l1b_Wi, Wi1t + (size_t)2048*256, 256, 2048, 256);
    transpose_conv_kernel<<<dim3(64, 32), 256, 0, stream>>>(l2f_Wi, Wi2t,                    1024, 2048, 1024);
    transpose_conv_kernel<<<dim3(64, 32), 256, 0, stream>>>(l2b_Wi, Wi2t + (size_t)2048*1024, 1024, 2048, 1024);
    transpose_conv_kernel<<<dim3(32, 96), 256, 0, stream>>>(W1, W1t, 3072, 1024, 3072);
    transpose_conv_kernel<<<dim3(16, 32), 256, 0, stream>>>(W2, W2t, 1024, 512, 1024);

    pool_kernel<<<dim3(8, BB), 256, 0, stream>>>(enc, pooled);
    embed_kernel<<<dim3(BB * TT), 256, 0, stream>>>(seq, emb, tok);

    const size_t xwdir = (size_t)TT * BB * 2048;

    // ---- layer 1: xw = tok @ Wi^T + b (per dir), then 64-step persistent kernel ----
    dense_mfma<<<dim3(32, 128), 256, 0, stream>>>(tok, Wi1t,                    l1f_b, xw,         16384, 2048, 256, 0, 1);
    dense_mfma<<<dim3(32, 128), 256, 0, stream>>>(tok, Wi1t + (size_t)2048*256, l1b_b, xw + xwdir, 16384, 2048, 256, 0, 1);
    lstm_layer_kernel<<<dim3(32), 256, 0, stream>>>(xw, Wh1t, seq, lstm1out, nullptr);

    // ---- layer 2 ----
    dense_mfma<<<dim3(32, 128), 256, 0, stream>>>(lstm1out, Wi2t,                     l2f_b, xw,         16384, 2048, 1024, 0, 1);
    dense_mfma<<<dim3(32, 128), 256, 0, stream>>>(lstm1out, Wi2t + (size_t)2048*1024, l2b_b, xw + xwdir, 16384, 2048, 1024, 0, 1);
    lstm_layer_kernel<<<dim3(32), 256, 0, stream>>>(xw, Wh2t, seq, nullptr, h2final);

    // ---- head ----
    concat_kernel<<<dim3(BB), 256, 0, stream>>>(pooled, h2final, feats);
    dense_mfma<<<dim3(16, 2), 256, 0, stream>>>(feats, W1t, b1, x1, BB, 1024, 3072, 1, 0);
    dense_mfma<<<dim3(8, 2),  256, 0, stream>>>(x1, W2t, b2, x2, BB, 512, 1024, 1, 0);
    final_kernel<<<dim3(BB), 256, 0, stream>>>(x2, W3, b3, (float*)d_out);
}

// Round 4
// 3109.697 us; speedup vs baseline: 3.4608x; 3.4608x over previous
//
#include <hip/hip_runtime.h>
#include <hip/hip_bf16.h>
#include <math.h>

#define BB 256
#define TT 64
#define UU 512
#define XWD 33554432   // per-dir xw elements (64*256*2048)

typedef __hip_bfloat16 bf16;
typedef __attribute__((ext_vector_type(8))) short sh8;     // 8 x bf16
typedef __attribute__((ext_vector_type(4))) short sh4;     // 4 x bf16
typedef __attribute__((ext_vector_type(4))) float floatx4; // MFMA acc

__device__ __forceinline__ float bf2f(short s) {
    union { unsigned int u; float f; } v;
    v.u = ((unsigned int)(unsigned short)s) << 16;
    return v.f;
}
__device__ __forceinline__ float fsig(float x)  { return 1.0f / (1.0f + __expf(-x)); }
__device__ __forceinline__ float ftanh(float x) { return 2.0f / (1.0f + __expf(-2.0f * x)) - 1.0f; }

// ---------------- transpose + fp32->bf16 convert ----------------
// in: [K x N] fp32 row-major. out[n * out_stride + k] = bf16(in[k][n]).
__global__ void transpose_conv_kernel(const float* __restrict__ in, bf16* __restrict__ out,
                                      int K, int N, int out_stride) {
    __shared__ float tile[32][33];
    int k0 = blockIdx.y * 32;
    int n0 = blockIdx.x * 32;
    int tid = threadIdx.x;
    int nn = tid & 31, kk = tid >> 5;
    #pragma unroll
    for (int j = 0; j < 4; ++j)
        tile[kk + j * 8][nn] = in[(size_t)(k0 + kk + j * 8) * N + n0 + nn];
    __syncthreads();
    int kk2 = tid & 31, nn2 = tid >> 5;
    #pragma unroll
    for (int j = 0; j < 4; ++j)
        out[(size_t)(n0 + nn2 + j * 8) * out_stride + k0 + kk2] =
            __float2bfloat16(tile[kk2][nn2 + j * 8]);
}

// ---------------- mean-pool over 10x10 spatial ----------------
__global__ void pool_kernel(const float* __restrict__ enc, float* __restrict__ pooled) {
    int b = blockIdx.y;
    int e = blockIdx.x * 256 + threadIdx.x;
    const float* p = enc + (size_t)b * 100 * 2048 + e;
    float s = 0.f;
    #pragma unroll 4
    for (int i = 0; i < 100; ++i) s += p[(size_t)i * 2048];
    pooled[(size_t)b * 2048 + e] = s * 0.01f;
}

// ---------------- embedding gather -> bf16, [t][b][256] layout ----------------
__global__ void embed_kernel(const int* __restrict__ seq, const float* __restrict__ emb,
                             bf16* __restrict__ tok) {
    int i = blockIdx.x;            // b*T + t
    int e = threadIdx.x;
    int b = i >> 6, t = i & 63;
    tok[((size_t)t * BB + b) * 256 + e] = __float2bfloat16(emb[(size_t)seq[i] * 256 + e]);
}

// ---------------- dense MFMA: out = act(A @ Wt^T + b) ----------------
// A: [M x K] bf16 row-major. Wt: [N x K] bf16. bias fp32.
// Block 128(M) x 64(N), 4 waves; wave = 64M x 32N (4x2 frags).
// mode 0: out[m][n] row-major bf16 (+optional relu).
// mode 2: xw-permuted store for lstm_step acc-init. M rows are m = t*256 + b.
//   idx = (((t*64 + (b>>2))*32 + ((n>>4)&31))*16 + (n&15))*16 + (n>>9)*4 + (b&3)
__global__ __launch_bounds__(256)
void dense_mfma(const bf16* __restrict__ A, const bf16* __restrict__ Wt,
                const float* __restrict__ bias, bf16* __restrict__ out,
                int M, int N, int K, int relu, int mode) {
    const int tid = threadIdx.x;
    const int w = tid >> 6, lane = tid & 63;
    const int lm = lane & 15, q = lane >> 4;
    const int r0 = blockIdx.y * 128 + (w & 1) * 64;
    const int c0 = blockIdx.x * 64 + (w >> 1) * 32;

    floatx4 acc[4][2];
    #pragma unroll
    for (int i = 0; i < 4; ++i)
        #pragma unroll
        for (int j = 0; j < 2; ++j) acc[i][j] = (floatx4){0.f, 0.f, 0.f, 0.f};

    const bf16* ar[4];
    const bf16* wr[2];
    #pragma unroll
    for (int i = 0; i < 4; ++i) ar[i] = A + (size_t)(r0 + i * 16 + lm) * K + q * 8;
    #pragma unroll
    for (int j = 0; j < 2; ++j) wr[j] = Wt + (size_t)(c0 + j * 16 + lm) * K + q * 8;

    for (int k0 = 0; k0 < K; k0 += 32) {
        sh8 a0 = *(const sh8*)(ar[0] + k0);
        sh8 a1 = *(const sh8*)(ar[1] + k0);
        sh8 a2 = *(const sh8*)(ar[2] + k0);
        sh8 a3 = *(const sh8*)(ar[3] + k0);
        sh8 b0 = *(const sh8*)(wr[0] + k0);
        sh8 b1 = *(const sh8*)(wr[1] + k0);
        acc[0][0] = __builtin_amdgcn_mfma_f32_16x16x32_bf16(a0, b0, acc[0][0], 0, 0, 0);
        acc[0][1] = __builtin_amdgcn_mfma_f32_16x16x32_bf16(a0, b1, acc[0][1], 0, 0, 0);
        acc[1][0] = __builtin_amdgcn_mfma_f32_16x16x32_bf16(a1, b0, acc[1][0], 0, 0, 0);
        acc[1][1] = __builtin_amdgcn_mfma_f32_16x16x32_bf16(a1, b1, acc[1][1], 0, 0, 0);
        acc[2][0] = __builtin_amdgcn_mfma_f32_16x16x32_bf16(a2, b0, acc[2][0], 0, 0, 0);
        acc[2][1] = __builtin_amdgcn_mfma_f32_16x16x32_bf16(a2, b1, acc[2][1], 0, 0, 0);
        acc[3][0] = __builtin_amdgcn_mfma_f32_16x16x32_bf16(a3, b0, acc[3][0], 0, 0, 0);
        acc[3][1] = __builtin_amdgcn_mfma_f32_16x16x32_bf16(a3, b1, acc[3][1], 0, 0, 0);
    }

    if (mode == 0) {
        #pragma unroll
        for (int i = 0; i < 4; ++i)
            #pragma unroll
            for (int j = 0; j < 2; ++j) {
                int col = c0 + j * 16 + lm;
                float bv = bias[col];
                #pragma unroll
                for (int r = 0; r < 4; ++r) {
                    int m = r0 + i * 16 + q * 4 + r;
                    float v = acc[i][j][r] + bv;
                    if (relu) v = fmaxf(v, 0.f);
                    out[(size_t)m * N + col] = __float2bfloat16(v);
                }
            }
    } else {
        // mode 2: m = t*256+b ; 4 consecutive r = 4 consecutive b (same t)
        #pragma unroll
        for (int i = 0; i < 4; ++i) {
            int mb = r0 + i * 16 + q * 4;     // r=0 element; mb&3 == 0
            int t = mb >> 8;
            int bq = (mb >> 2) & 63;
            #pragma unroll
            for (int j = 0; j < 2; ++j) {
                int n = c0 + j * 16 + lm;
                float bv = bias[n];
                size_t base = ((((size_t)(t * 64 + bq) * 32 + ((n >> 4) & 31)) * 16
                               + (n & 15)) * 16) + (n >> 9) * 4;
                sh4 sv;
                #pragma unroll
                for (int r = 0; r < 4; ++r) {
                    union { float f; unsigned u; } v; v.f = acc[i][j][r] + bv;
                    unsigned rr = v.u + 0x7fff + ((v.u >> 16) & 1);
                    sv[r] = (short)(rr >> 16);
                }
                *(sh4*)(out + base) = sv;
            }
        }
    }
}

// ---------------- per-step LSTM: z = xw(t) + h@Wh^T; gates; mask carry ----------------
// grid (32 u-tiles, 4 b-groups, 2 dirs) = 256 blocks, 4 waves (waves split 64b by 16).
// Wave tile: 16 b x 16 u x 4 gates. A = h rows, B = Wh rows. No LDS, no syncthreads.
// Wht: [dir][n=g*512+u][512] k-contig. xw: mode-2 perm (see dense_mfma). h,c: [dir][b][512].
__global__ __launch_bounds__(256)
void lstm_step(const bf16* __restrict__ xw, const bf16* __restrict__ Wht,
               const int* __restrict__ seq,
               const bf16* __restrict__ hin, bf16* __restrict__ hout,
               float* __restrict__ c, bf16* __restrict__ seqout, int s) {
    const int dir = blockIdx.z;
    const int t = dir ? (TT - 1 - s) : s;
    const int u0 = blockIdx.x * 16;
    const int tid = threadIdx.x;
    const int w = tid >> 6, lane = tid & 63;
    const int lm = lane & 15, q = lane >> 4;
    const int b0w = blockIdx.y * 64 + w * 16;

    const size_t hdb = (size_t)dir * BB * UU;
    const bf16* hA = hin + hdb + (size_t)(b0w + lm) * UU + q * 8;
    const bf16* Wd = Wht + (size_t)dir * 2048 * UU;
    const bf16* wp0 = Wd + (size_t)(0 * UU + u0 + lm) * UU + q * 8;
    const bf16* wp1 = Wd + (size_t)(1 * UU + u0 + lm) * UU + q * 8;
    const bf16* wp2 = Wd + (size_t)(2 * UU + u0 + lm) * UU + q * 8;
    const bf16* wp3 = Wd + (size_t)(3 * UU + u0 + lm) * UU + q * 8;

    // acc init from permuted xw: one 32 B run per lane
    const bf16* xwp = xw + (size_t)dir * XWD
        + (((size_t)(t * 64 + (b0w >> 2) + q) * 32 + (u0 >> 4)) * 16 + lm) * 16;
    sh8 x0 = *(const sh8*)xwp;
    sh8 x1 = *(const sh8*)(xwp + 8);
    floatx4 acc0 = {bf2f(x0[0]), bf2f(x0[1]), bf2f(x0[2]), bf2f(x0[3])};
    floatx4 acc1 = {bf2f(x0[4]), bf2f(x0[5]), bf2f(x0[6]), bf2f(x0[7])};
    floatx4 acc2 = {bf2f(x1[0]), bf2f(x1[1]), bf2f(x1[2]), bf2f(x1[3])};
    floatx4 acc3 = {bf2f(x1[4]), bf2f(x1[5]), bf2f(x1[6]), bf2f(x1[7])};

    #pragma unroll
    for (int kc = 0; kc < 16; ++kc) {
        sh8 hv = *(const sh8*)(hA + kc * 32);
        sh8 a0 = *(const sh8*)(wp0 + kc * 32);
        sh8 a1 = *(const sh8*)(wp1 + kc * 32);
        sh8 a2 = *(const sh8*)(wp2 + kc * 32);
        sh8 a3 = *(const sh8*)(wp3 + kc * 32);
        acc0 = __builtin_amdgcn_mfma_f32_16x16x32_bf16(hv, a0, acc0, 0, 0, 0);
        acc1 = __builtin_amdgcn_mfma_f32_16x16x32_bf16(hv, a1, acc1, 0, 0, 0);
        acc2 = __builtin_amdgcn_mfma_f32_16x16x32_bf16(hv, a2, acc2, 0, 0, 0);
        acc3 = __builtin_amdgcn_mfma_f32_16x16x32_bf16(hv, a3, acc3, 0, 0, 0);
    }

    // epilogue: lane holds (b = b0w+q*4+r, u = u0+lm), all 4 gates in-lane
    const int uu = u0 + lm;
    #pragma unroll
    for (int r = 0; r < 4; ++r) {
        int b = b0w + q * 4 + r;
        bool m = (seq[b * TT + t] != 0);
        size_t off = hdb + (size_t)b * UU + uu;
        float cp = c[off];
        float cn = fsig(acc1[r]) * cp + fsig(acc0[r]) * ftanh(acc2[r]);
        float hn = fsig(acc3[r]) * ftanh(cn);
        float hp = __bfloat162float(hin[off]);
        float hv2 = m ? hn : hp;
        c[off] = m ? cn : cp;
        hout[off] = __float2bfloat16(hv2);
        if (seqout)
            seqout[((size_t)t * BB + b) * 1024 + dir * UU + uu] = __float2bfloat16(hv2);
    }
}

// ---------------- feats = [pooled | h2f | h2b] (bf16) ----------------
__global__ void concat_kernel(const float* __restrict__ pooled, const bf16* __restrict__ h2,
                              bf16* __restrict__ feats) {
    int b = blockIdx.x;
    for (int j = threadIdx.x; j < 3072; j += 256) {
        bf16 v;
        if (j < 2048) v = __float2bfloat16(pooled[(size_t)b * 2048 + j]);
        else {
            int u = j - 2048;
            int dir = u >> 9;
            int uu = u & 511;
            v = h2[((size_t)dir * BB + b) * UU + uu];
        }
        feats[(size_t)b * 3072 + j] = v;
    }
}

// ---------------- out = sigmoid(x2 @ W3 + b3), K=512 ----------------
__global__ void final_kernel(const bf16* __restrict__ x2, const float* __restrict__ W3,
                             const float* __restrict__ b3, float* __restrict__ out) {
    int b = blockIdx.x;
    int tid = threadIdx.x;
    float v = __bfloat162float(x2[(size_t)b * 512 + tid]) * W3[tid]
            + __bfloat162float(x2[(size_t)b * 512 + 256 + tid]) * W3[256 + tid];
    for (int off = 32; off > 0; off >>= 1) v += __shfl_down(v, off, 64);
    __shared__ float wsum[4];
    if ((tid & 63) == 0) wsum[tid >> 6] = v;
    __syncthreads();
    if (tid == 0) {
        float sum = wsum[0] + wsum[1] + wsum[2] + wsum[3] + b3[0];
        out[b] = 1.0f / (1.0f + expf(-sum));
    }
}

extern "C" void kernel_launch(void* const* d_in, const int* in_sizes, int n_in,
                              void* d_out, int out_size, void* d_ws, size_t ws_size,
                              hipStream_t stream) {
    const float* enc    = (const float*)d_in[0];
    const int*   seq    = (const int*)  d_in[1];
    const float* emb    = (const float*)d_in[2];
    const float* l1f_Wi = (const float*)d_in[3];
    const float* l1f_Wh = (const float*)d_in[4];
    const float* l1f_b  = (const float*)d_in[5];
    const float* l1b_Wi = (const float*)d_in[6];
    const float* l1b_Wh = (const float*)d_in[7];
    const float* l1b_b  = (const float*)d_in[8];
    const float* l2f_Wi = (const float*)d_in[9];
    const float* l2f_Wh = (const float*)d_in[10];
    const float* l2f_b  = (const float*)d_in[11];
    const float* l2b_Wi = (const float*)d_in[12];
    const float* l2b_Wh = (const float*)d_in[13];
    const float* l2b_b  = (const float*)d_in[14];
    const float* W1     = (const float*)d_in[15];
    const float* b1     = (const float*)d_in[16];
    const float* W2     = (const float*)d_in[17];
    const float* b2     = (const float*)d_in[18];
    const float* W3     = (const float*)d_in[19];
    const float* b3     = (const float*)d_in[20];

    // ---- workspace layout, ~205 MB ----
    char* p = (char*)d_ws;
    bf16* tok      = (bf16*)p;  p += (size_t)TT * BB * 256 * 2;        // [t][b][256]
    bf16* lstm1out = (bf16*)p;  p += (size_t)TT * BB * 1024 * 2;       // [t][b][1024]
    bf16* xw       = (bf16*)p;  p += (size_t)2 * XWD * 2;              // mode-2 perm
    bf16* Wh1t     = (bf16*)p;  p += (size_t)2 * 2048 * 512 * 2;
    bf16* Wh2t     = (bf16*)p;  p += (size_t)2 * 2048 * 512 * 2;
    bf16* Wi1t     = (bf16*)p;  p += (size_t)2 * 2048 * 256 * 2;
    bf16* Wi2t     = (bf16*)p;  p += (size_t)2 * 2048 * 1024 * 2;
    bf16* W1t      = (bf16*)p;  p += (size_t)1024 * 3072 * 2;
    bf16* W2t      = (bf16*)p;  p += (size_t)512 * 1024 * 2;
    float* pooled  = (float*)p; p += (size_t)BB * 2048 * 4;
    bf16* feats    = (bf16*)p;  p += (size_t)BB * 3072 * 2;
    bf16* x1       = (bf16*)p;  p += (size_t)BB * 1024 * 2;
    bf16* x2       = (bf16*)p;  p += (size_t)BB * 512 * 2;
    bf16* hb0      = (bf16*)p;  p += (size_t)2 * BB * UU * 2;
    bf16* hb1      = (bf16*)p;  p += (size_t)2 * BB * UU * 2;
    float* cbuf    = (float*)p; p += (size_t)2 * BB * UU * 4;

    // ---- weight transposes (one-time per call) ----
    transpose_conv_kernel<<<dim3(64, 16), 256, 0, stream>>>(l1f_Wh, Wh1t,                    512, 2048, 512);
    transpose_conv_kernel<<<dim3(64, 16), 256, 0, stream>>>(l1b_Wh, Wh1t + (size_t)2048*512, 512, 2048, 512);
    transpose_conv_kernel<<<dim3(64, 16), 256, 0, stream>>>(l2f_Wh, Wh2t,                    512, 2048, 512);
    transpose_conv_kernel<<<dim3(64, 16), 256, 0, stream>>>(l2b_Wh, Wh2t + (size_t)2048*512, 512, 2048, 512);
    transpose_conv_kernel<<<dim3(64, 8),  256, 0, stream>>>(l1f_Wi, Wi1t,                    256, 2048, 256);
    transpose_conv_kernel<<<dim3(64, 8),  256, 0, stream>>>(l1b_Wi, Wi1t + (size_t)2048*256, 256, 2048, 256);
    transpose_conv_kernel<<<dim3(64, 32), 256, 0, stream>>>(l2f_Wi, Wi2t,                     1024, 2048, 1024);
    transpose_conv_kernel<<<dim3(64, 32), 256, 0, stream>>>(l2b_Wi, Wi2t + (size_t)2048*1024, 1024, 2048, 1024);
    transpose_conv_kernel<<<dim3(32, 96), 256, 0, stream>>>(W1, W1t, 3072, 1024, 3072);
    transpose_conv_kernel<<<dim3(16, 32), 256, 0, stream>>>(W2, W2t, 1024, 512, 1024);

    pool_kernel<<<dim3(8, BB), 256, 0, stream>>>(enc, pooled);
    embed_kernel<<<dim3(BB * TT), 256, 0, stream>>>(seq, emb, tok);

    // ---- layer 1: xw = tok @ Wi1^T + b (mode-2 perm), then 64 step launches ----
    hipMemsetAsync(hb0, 0, (size_t)2 * BB * UU * 2, stream);
    hipMemsetAsync(cbuf, 0, (size_t)2 * BB * UU * 4, stream);
    dense_mfma<<<dim3(32, 128), 256, 0, stream>>>(tok, Wi1t,                    l1f_b, xw,       16384, 2048, 256, 0, 2);
    dense_mfma<<<dim3(32, 128), 256, 0, stream>>>(tok, Wi1t + (size_t)2048*256, l1b_b, xw + XWD, 16384, 2048, 256, 0, 2);
    for (int s = 0; s < TT; ++s) {
        const bf16* hin = (s & 1) ? hb1 : hb0;
        bf16*      hout = (s & 1) ? hb0 : hb1;
        lstm_step<<<dim3(32, 4, 2), 256, 0, stream>>>(xw, Wh1t, seq, hin, hout, cbuf, lstm1out, s);
    }

    // ---- layer 2 ----
    hipMemsetAsync(hb0, 0, (size_t)2 * BB * UU * 2, stream);
    hipMemsetAsync(cbuf, 0, (size_t)2 * BB * UU * 4, stream);
    dense_mfma<<<dim3(32, 128), 256, 0, stream>>>(lstm1out, Wi2t,                     l2f_b, xw,       16384, 2048, 1024, 0, 2);
    dense_mfma<<<dim3(32, 128), 256, 0, stream>>>(lstm1out, Wi2t + (size_t)2048*1024, l2b_b, xw + XWD, 16384, 2048, 1024, 0, 2);
    for (int s = 0; s < TT; ++s) {
        const bf16* hin = (s & 1) ? hb1 : hb0;
        bf16*      hout = (s & 1) ? hb0 : hb1;
        lstm_step<<<dim3(32, 4, 2), 256, 0, stream>>>(xw, Wh2t, seq, hin, hout, cbuf, nullptr, s);
    }
    // s=63 writes hout=hb0 -> final h2 in hb0

    // ---- head ----
    concat_kernel<<<dim3(BB), 256, 0, stream>>>(pooled, hb0, feats);
    dense_mfma<<<dim3(16, 2), 256, 0, stream>>>(feats, W1t, b1, x1, BB, 1024, 3072, 1, 0);
    dense_mfma<<<dim3(8, 2),  256, 0, stream>>>(x1, W2t, b2, x2, BB, 512, 1024, 1, 0);
    final_kernel<<<dim3(BB), 256, 0, stream>>>(x2, W3, b3, (float*)d_out);
}

// Round 5
// 2632.773 us; speedup vs baseline: 4.0878x; 1.1811x over previous
//
#include <hip/hip_runtime.h>
#include <hip/hip_bf16.h>
#include <math.h>

#define BB 256
#define TT 64
#define UU 512
#define XWD 33554432   // per-dir xw elements (64*256*2048)

typedef __hip_bfloat16 bf16;
typedef __attribute__((ext_vector_type(8))) short sh8;     // 8 x bf16
typedef __attribute__((ext_vector_type(4))) short sh4;     // 4 x bf16
typedef __attribute__((ext_vector_type(4))) float floatx4; // MFMA acc

__device__ __forceinline__ float bf2f(short s) {
    union { unsigned int u; float f; } v;
    v.u = ((unsigned int)(unsigned short)s) << 16;
    return v.f;
}
__device__ __forceinline__ float fsig(float x)  { return 1.0f / (1.0f + __expf(-x)); }
__device__ __forceinline__ float ftanh(float x) { return 2.0f / (1.0f + __expf(-2.0f * x)) - 1.0f; }

// async global->LDS, 16B per lane. LDS dest must be wave-uniform base + lane*16.
#define GLDS(gp, lp) __builtin_amdgcn_global_load_lds( \
    (const __attribute__((address_space(1))) unsigned int*)(const void*)(gp), \
    (__attribute__((address_space(3))) unsigned int*)(void*)(lp), 16, 0, 0)

// ---------------- transpose + fp32->bf16 convert ----------------
// in: [K x N] fp32 row-major. out[n * out_stride + k] = bf16(in[k][n]).
__global__ void transpose_conv_kernel(const float* __restrict__ in, bf16* __restrict__ out,
                                      int K, int N, int out_stride) {
    __shared__ float tile[32][33];
    int k0 = blockIdx.y * 32;
    int n0 = blockIdx.x * 32;
    int tid = threadIdx.x;
    int nn = tid & 31, kk = tid >> 5;
    #pragma unroll
    for (int j = 0; j < 4; ++j)
        tile[kk + j * 8][nn] = in[(size_t)(k0 + kk + j * 8) * N + n0 + nn];
    __syncthreads();
    int kk2 = tid & 31, nn2 = tid >> 5;
    #pragma unroll
    for (int j = 0; j < 4; ++j)
        out[(size_t)(n0 + nn2 + j * 8) * out_stride + k0 + kk2] =
            __float2bfloat16(tile[kk2][nn2 + j * 8]);
}

// ---------------- mean-pool over 10x10 spatial ----------------
__global__ void pool_kernel(const float* __restrict__ enc, float* __restrict__ pooled) {
    int b = blockIdx.y;
    int e = blockIdx.x * 256 + threadIdx.x;
    const float* p = enc + (size_t)b * 100 * 2048 + e;
    float s = 0.f;
    #pragma unroll 4
    for (int i = 0; i < 100; ++i) s += p[(size_t)i * 2048];
    pooled[(size_t)b * 2048 + e] = s * 0.01f;
}

// ---------------- embedding gather -> bf16, [t][b][256] layout ----------------
__global__ void embed_kernel(const int* __restrict__ seq, const float* __restrict__ emb,
                             bf16* __restrict__ tok) {
    int i = blockIdx.x;            // b*T + t
    int e = threadIdx.x;
    int b = i >> 6, t = i & 63;
    tok[((size_t)t * BB + b) * 256 + e] = __float2bfloat16(emb[(size_t)seq[i] * 256 + e]);
}

// ---------------- LDS-staged GEMM: out = act(A @ Wt^T + b) ----------------
// A: [M x K] bf16 row-major. Wt: [N x K] bf16. bias fp32. M,N mult of 128, K mult of 32.
// Block 256 thr = 4 waves, tile 128M x 128N, BK=32, global_load_lds(16B) staging,
// wave = 64x64 (4x4 frags, 16 MFMA / 8 ds_read_b128 per K-chunk). 2-barrier K-loop.
// mode 0: out[m][n] bf16 (+relu). mode 2: xw-permuted store (m = t*256+b):
//   base = (((t*64 + (m>>2)&63)*32 + (n>>4)&31)*16 + (n&15))*16 + (n>>9)*4, sv packs 4 b.
__global__ __launch_bounds__(256)
void gemm_tile(const bf16* __restrict__ A, const bf16* __restrict__ Wt,
               const float* __restrict__ bias, bf16* __restrict__ out,
               int M, int N, int K, int relu, int mode) {
    __shared__ __align__(16) bf16 As[128 * 32];
    __shared__ __align__(16) bf16 Bs[128 * 32];
    const int tid = threadIdx.x;
    const int w = tid >> 6, lane = tid & 63;
    const int lm = lane & 15, q = lane >> 4;
    const int m0 = blockIdx.y * 128;
    const int n0 = blockIdx.x * 128;
    const int wm = (w & 1) * 64, wn = (w >> 1) * 64;

    // staging: thread covers row srow (and srow+64), k-quarter sk8. LDS off = tid*8 elems.
    const int srow = tid >> 2;
    const int sk8  = (tid & 3) * 8;
    const bf16* ga0 = A  + (size_t)(m0 + srow) * K + sk8;
    const bf16* ga1 = A  + (size_t)(m0 + 64 + srow) * K + sk8;
    const bf16* gb0 = Wt + (size_t)(n0 + srow) * K + sk8;
    const bf16* gb1 = Wt + (size_t)(n0 + 64 + srow) * K + sk8;
    bf16* la0 = As + tid * 8;
    bf16* la1 = As + 2048 + tid * 8;
    bf16* lb0 = Bs + tid * 8;
    bf16* lb1 = Bs + 2048 + tid * 8;

    floatx4 acc[4][4];
    #pragma unroll
    for (int i = 0; i < 4; ++i)
        #pragma unroll
        for (int j = 0; j < 4; ++j) acc[i][j] = (floatx4){0.f, 0.f, 0.f, 0.f};

    const bf16* ra[4];
    const bf16* rb[4];
    #pragma unroll
    for (int i = 0; i < 4; ++i) ra[i] = As + (wm + i * 16 + lm) * 32 + q * 8;
    #pragma unroll
    for (int j = 0; j < 4; ++j) rb[j] = Bs + (wn + j * 16 + lm) * 32 + q * 8;

    for (int k0 = 0; k0 < K; k0 += 32) {
        GLDS(ga0 + k0, la0);
        GLDS(ga1 + k0, la1);
        GLDS(gb0 + k0, lb0);
        GLDS(gb1 + k0, lb1);
        __syncthreads();
        sh8 af[4], bfr[4];
        #pragma unroll
        for (int i = 0; i < 4; ++i) af[i] = *(const sh8*)ra[i];
        #pragma unroll
        for (int j = 0; j < 4; ++j) bfr[j] = *(const sh8*)rb[j];
        #pragma unroll
        for (int i = 0; i < 4; ++i)
            #pragma unroll
            for (int j = 0; j < 4; ++j)
                acc[i][j] = __builtin_amdgcn_mfma_f32_16x16x32_bf16(af[i], bfr[j], acc[i][j], 0, 0, 0);
        __syncthreads();
    }

    if (mode == 0) {
        #pragma unroll
        for (int i = 0; i < 4; ++i)
            #pragma unroll
            for (int j = 0; j < 4; ++j) {
                int n = n0 + wn + j * 16 + lm;
                float bv = bias[n];
                #pragma unroll
                for (int r = 0; r < 4; ++r) {
                    int m = m0 + wm + i * 16 + q * 4 + r;
                    float v = acc[i][j][r] + bv;
                    if (relu) v = fmaxf(v, 0.f);
                    out[(size_t)m * N + n] = __float2bfloat16(v);
                }
            }
    } else {
        #pragma unroll
        for (int i = 0; i < 4; ++i) {
            int mb = m0 + wm + i * 16 + q * 4;    // mb&3 == 0; 4 r = 4 consecutive b, same t
            int t = mb >> 8;
            int bq = (mb >> 2) & 63;
            #pragma unroll
            for (int j = 0; j < 4; ++j) {
                int n = n0 + wn + j * 16 + lm;
                float bv = bias[n];
                size_t base = ((((size_t)(t * 64 + bq) * 32 + ((n >> 4) & 31)) * 16
                               + (n & 15)) * 16) + (n >> 9) * 4;
                sh4 sv;
                #pragma unroll
                for (int r = 0; r < 4; ++r) {
                    union { float f; unsigned u; } v; v.f = acc[i][j][r] + bv;
                    unsigned rr = v.u + 0x7fff + ((v.u >> 16) & 1);
                    sv[r] = (short)(rr >> 16);
                }
                *(sh4*)(out + base) = sv;
            }
        }
    }
}

// ---------------- per-step LSTM, k-split for occupancy ----------------
// grid (32 u-tiles, 4 b-groups, 2 dirs) = 256 blocks, 512 thr = 8 waves.
// Waves 0-3 (kh=0): b-group wb, kc 0..7, acc init from permuted xw (bias pre-added).
// Waves 4-7 (kh=1): same b-groups, kc 8..15, partials -> LDS (stride 17, conflict-free).
// Waves 0-3 combine + gates i,f,g,o + mask carry + h stores. No cross-step global for h@Wh.
__global__ __launch_bounds__(512)
void lstm_step(const bf16* __restrict__ xw, const bf16* __restrict__ Wht,
               const int* __restrict__ seq,
               const bf16* __restrict__ hin, bf16* __restrict__ hout,
               float* __restrict__ c, bf16* __restrict__ seqout, int s) {
    const int dir = blockIdx.z;
    const int t = dir ? (TT - 1 - s) : s;
    const int u0 = blockIdx.x * 16;
    const int tid = threadIdx.x;
    const int w = tid >> 6, lane = tid & 63;
    const int lm = lane & 15, q = lane >> 4;
    const int kh = w >> 2;           // k-half
    const int wb = w & 3;            // b-group wave
    const int b0w = blockIdx.y * 64 + wb * 16;

    __shared__ float part[4 * 64 * 17];   // [wb][lane][16+pad]

    const size_t hdb = (size_t)dir * BB * UU;
    const int koff = kh * 256;            // 8 kc * 32
    const bf16* hA = hin + hdb + (size_t)(b0w + lm) * UU + q * 8 + koff;
    const bf16* Wd = Wht + (size_t)dir * 2048 * UU;
    const bf16* wp0 = Wd + (size_t)(0 * UU + u0 + lm) * UU + q * 8 + koff;
    const bf16* wp1 = Wd + (size_t)(1 * UU + u0 + lm) * UU + q * 8 + koff;
    const bf16* wp2 = Wd + (size_t)(2 * UU + u0 + lm) * UU + q * 8 + koff;
    const bf16* wp3 = Wd + (size_t)(3 * UU + u0 + lm) * UU + q * 8 + koff;

    floatx4 acc0, acc1, acc2, acc3;
    if (kh == 0) {
        // acc init from permuted xw: one 32B run per lane
        const bf16* xwp = xw + (size_t)dir * XWD
            + (((size_t)(t * 64 + (b0w >> 2) + q) * 32 + (u0 >> 4)) * 16 + lm) * 16;
        sh8 x0 = *(const sh8*)xwp;
        sh8 x1 = *(const sh8*)(xwp + 8);
        acc0 = (floatx4){bf2f(x0[0]), bf2f(x0[1]), bf2f(x0[2]), bf2f(x0[3])};
        acc1 = (floatx4){bf2f(x0[4]), bf2f(x0[5]), bf2f(x0[6]), bf2f(x0[7])};
        acc2 = (floatx4){bf2f(x1[0]), bf2f(x1[1]), bf2f(x1[2]), bf2f(x1[3])};
        acc3 = (floatx4){bf2f(x1[4]), bf2f(x1[5]), bf2f(x1[6]), bf2f(x1[7])};
    } else {
        acc0 = acc1 = acc2 = acc3 = (floatx4){0.f, 0.f, 0.f, 0.f};
    }

    #pragma unroll
    for (int kc = 0; kc < 8; ++kc) {
        sh8 hv = *(const sh8*)(hA + kc * 32);
        sh8 a0 = *(const sh8*)(wp0 + kc * 32);
        sh8 a1 = *(const sh8*)(wp1 + kc * 32);
        sh8 a2 = *(const sh8*)(wp2 + kc * 32);
        sh8 a3 = *(const sh8*)(wp3 + kc * 32);
        acc0 = __builtin_amdgcn_mfma_f32_16x16x32_bf16(hv, a0, acc0, 0, 0, 0);
        acc1 = __builtin_amdgcn_mfma_f32_16x16x32_bf16(hv, a1, acc1, 0, 0, 0);
        acc2 = __builtin_amdgcn_mfma_f32_16x16x32_bf16(hv, a2, acc2, 0, 0, 0);
        acc3 = __builtin_amdgcn_mfma_f32_16x16x32_bf16(hv, a3, acc3, 0, 0, 0);
    }

    if (kh == 1) {
        float* pp = part + (wb * 64 + lane) * 17;
        #pragma unroll
        for (int r = 0; r < 4; ++r) {
            pp[r] = acc0[r]; pp[4 + r] = acc1[r];
            pp[8 + r] = acc2[r]; pp[12 + r] = acc3[r];
        }
    }
    __syncthreads();
    if (kh == 0) {
        const float* pp = part + (wb * 64 + lane) * 17;
        #pragma unroll
        for (int r = 0; r < 4; ++r) {
            acc0[r] += pp[r]; acc1[r] += pp[4 + r];
            acc2[r] += pp[8 + r]; acc3[r] += pp[12 + r];
        }
        // epilogue: lane holds (b = b0w+q*4+r, u = u0+lm)
        const int uu = u0 + lm;
        #pragma unroll
        for (int r = 0; r < 4; ++r) {
            int b = b0w + q * 4 + r;
            bool m = (seq[b * TT + t] != 0);
            size_t off = hdb + (size_t)b * UU + uu;
            float cp = c[off];
            float cn = fsig(acc1[r]) * cp + fsig(acc0[r]) * ftanh(acc2[r]);
            float hn = fsig(acc3[r]) * ftanh(cn);
            float hp = __bfloat162float(hin[off]);
            float hv2 = m ? hn : hp;
            c[off] = m ? cn : cp;
            hout[off] = __float2bfloat16(hv2);
            if (seqout)
                seqout[((size_t)t * BB + b) * 1024 + dir * UU + uu] = __float2bfloat16(hv2);
        }
    }
}

// ---------------- feats = [pooled | h2f | h2b] (bf16) ----------------
__global__ void concat_kernel(const float* __restrict__ pooled, const bf16* __restrict__ h2,
                              bf16* __restrict__ feats) {
    int b = blockIdx.x;
    for (int j = threadIdx.x; j < 3072; j += 256) {
        bf16 v;
        if (j < 2048) v = __float2bfloat16(pooled[(size_t)b * 2048 + j]);
        else {
            int u = j - 2048;
            int dir = u >> 9;
            int uu = u & 511;
            v = h2[((size_t)dir * BB + b) * UU + uu];
        }
        feats[(size_t)b * 3072 + j] = v;
    }
}

// ---------------- out = sigmoid(x2 @ W3 + b3), K=512 ----------------
__global__ void final_kernel(const bf16* __restrict__ x2, const float* __restrict__ W3,
                             const float* __restrict__ b3, float* __restrict__ out) {
    int b = blockIdx.x;
    int tid = threadIdx.x;
    float v = __bfloat162float(x2[(size_t)b * 512 + tid]) * W3[tid]
            + __bfloat162float(x2[(size_t)b * 512 + 256 + tid]) * W3[256 + tid];
    for (int off = 32; off > 0; off >>= 1) v += __shfl_down(v, off, 64);
    __shared__ float wsum[4];
    if ((tid & 63) == 0) wsum[tid >> 6] = v;
    __syncthreads();
    if (tid == 0) {
        float sum = wsum[0] + wsum[1] + wsum[2] + wsum[3] + b3[0];
        out[b] = 1.0f / (1.0f + expf(-sum));
    }
}

extern "C" void kernel_launch(void* const* d_in, const int* in_sizes, int n_in,
                              void* d_out, int out_size, void* d_ws, size_t ws_size,
                              hipStream_t stream) {
    const float* enc    = (const float*)d_in[0];
    const int*   seq    = (const int*)  d_in[1];
    const float* emb    = (const float*)d_in[2];
    const float* l1f_Wi = (const float*)d_in[3];
    const float* l1f_Wh = (const float*)d_in[4];
    const float* l1f_b  = (const float*)d_in[5];
    const float* l1b_Wi = (const float*)d_in[6];
    const float* l1b_Wh = (const float*)d_in[7];
    const float* l1b_b  = (const float*)d_in[8];
    const float* l2f_Wi = (const float*)d_in[9];
    const float* l2f_Wh = (const float*)d_in[10];
    const float* l2f_b  = (const float*)d_in[11];
    const float* l2b_Wi = (const float*)d_in[12];
    const float* l2b_Wh = (const float*)d_in[13];
    const float* l2b_b  = (const float*)d_in[14];
    const float* W1     = (const float*)d_in[15];
    const float* b1     = (const float*)d_in[16];
    const float* W2     = (const float*)d_in[17];
    const float* b2     = (const float*)d_in[18];
    const float* W3     = (const float*)d_in[19];
    const float* b3     = (const float*)d_in[20];

    // ---- workspace layout, ~205 MB ----
    char* p = (char*)d_ws;
    bf16* tok      = (bf16*)p;  p += (size_t)TT * BB * 256 * 2;        // [t][b][256]
    bf16* lstm1out = (bf16*)p;  p += (size_t)TT * BB * 1024 * 2;       // [t][b][1024]
    bf16* xw       = (bf16*)p;  p += (size_t)2 * XWD * 2;              // mode-2 perm
    bf16* Wh1t     = (bf16*)p;  p += (size_t)2 * 2048 * 512 * 2;
    bf16* Wh2t     = (bf16*)p;  p += (size_t)2 * 2048 * 512 * 2;
    bf16* Wi1t     = (bf16*)p;  p += (size_t)2 * 2048 * 256 * 2;
    bf16* Wi2t     = (bf16*)p;  p += (size_t)2 * 2048 * 1024 * 2;
    bf16* W1t      = (bf16*)p;  p += (size_t)1024 * 3072 * 2;
    bf16* W2t      = (bf16*)p;  p += (size_t)512 * 1024 * 2;
    float* pooled  = (float*)p; p += (size_t)BB * 2048 * 4;
    bf16* feats    = (bf16*)p;  p += (size_t)BB * 3072 * 2;
    bf16* x1       = (bf16*)p;  p += (size_t)BB * 1024 * 2;
    bf16* x2       = (bf16*)p;  p += (size_t)BB * 512 * 2;
    bf16* hb0      = (bf16*)p;  p += (size_t)2 * BB * UU * 2;
    bf16* hb1      = (bf16*)p;  p += (size_t)2 * BB * UU * 2;
    float* cbuf    = (float*)p; p += (size_t)2 * BB * UU * 4;

    // ---- weight transposes (one-time per call) ----
    transpose_conv_kernel<<<dim3(64, 16), 256, 0, stream>>>(l1f_Wh, Wh1t,                    512, 2048, 512);
    transpose_conv_kernel<<<dim3(64, 16), 256, 0, stream>>>(l1b_Wh, Wh1t + (size_t)2048*512, 512, 2048, 512);
    transpose_conv_kernel<<<dim3(64, 16), 256, 0, stream>>>(l2f_Wh, Wh2t,                    512, 2048, 512);
    transpose_conv_kernel<<<dim3(64, 16), 256, 0, stream>>>(l2b_Wh, Wh2t + (size_t)2048*512, 512, 2048, 512);
    transpose_conv_kernel<<<dim3(64, 8),  256, 0, stream>>>(l1f_Wi, Wi1t,                    256, 2048, 256);
    transpose_conv_kernel<<<dim3(64, 8),  256, 0, stream>>>(l1b_Wi, Wi1t + (size_t)2048*256, 256, 2048, 256);
    transpose_conv_kernel<<<dim3(64, 32), 256, 0, stream>>>(l2f_Wi, Wi2t,                     1024, 2048, 1024);
    transpose_conv_kernel<<<dim3(64, 32), 256, 0, stream>>>(l2b_Wi, Wi2t + (size_t)2048*1024, 1024, 2048, 1024);
    transpose_conv_kernel<<<dim3(32, 96), 256, 0, stream>>>(W1, W1t, 3072, 1024, 3072);
    transpose_conv_kernel<<<dim3(16, 32), 256, 0, stream>>>(W2, W2t, 1024, 512, 1024);

    pool_kernel<<<dim3(8, BB), 256, 0, stream>>>(enc, pooled);
    embed_kernel<<<dim3(BB * TT), 256, 0, stream>>>(seq, emb, tok);

    // ---- layer 1: xw = tok @ Wi1^T + b (mode-2 perm), then 64 step launches ----
    hipMemsetAsync(hb0, 0, (size_t)2 * BB * UU * 2, stream);
    hipMemsetAsync(cbuf, 0, (size_t)2 * BB * UU * 4, stream);
    gemm_tile<<<dim3(16, 128), 256, 0, stream>>>(tok, Wi1t,                    l1f_b, xw,       16384, 2048, 256, 0, 2);
    gemm_tile<<<dim3(16, 128), 256, 0, stream>>>(tok, Wi1t + (size_t)2048*256, l1b_b, xw + XWD, 16384, 2048, 256, 0, 2);
    for (int s = 0; s < TT; ++s) {
        const bf16* hin = (s & 1) ? hb1 : hb0;
        bf16*      hout = (s & 1) ? hb0 : hb1;
        lstm_step<<<dim3(32, 4, 2), 512, 0, stream>>>(xw, Wh1t, seq, hin, hout, cbuf, lstm1out, s);
    }

    // ---- layer 2 ----
    hipMemsetAsync(hb0, 0, (size_t)2 * BB * UU * 2, stream);
    hipMemsetAsync(cbuf, 0, (size_t)2 * BB * UU * 4, stream);
    gemm_tile<<<dim3(16, 128), 256, 0, stream>>>(lstm1out, Wi2t,                     l2f_b, xw,       16384, 2048, 1024, 0, 2);
    gemm_tile<<<dim3(16, 128), 256, 0, stream>>>(lstm1out, Wi2t + (size_t)2048*1024, l2b_b, xw + XWD, 16384, 2048, 1024, 0, 2);
    for (int s = 0; s < TT; ++s) {
        const bf16* hin = (s & 1) ? hb1 : hb0;
        bf16*      hout = (s & 1) ? hb0 : hb1;
        lstm_step<<<dim3(32, 4, 2), 512, 0, stream>>>(xw, Wh2t, seq, hin, hout, cbuf, nullptr, s);
    }
    // s=63 writes hout=hb0 -> final h2 in hb0

    // ---- head ----
    concat_kernel<<<dim3(BB), 256, 0, stream>>>(pooled, hb0, feats);
    gemm_tile<<<dim3(8, 2), 256, 0, stream>>>(feats, W1t, b1, x1, BB, 1024, 3072, 1, 0);
    gemm_tile<<<dim3(4, 2), 256, 0, stream>>>(x1, W2t, b2, x2, BB, 512, 1024, 1, 0);
    final_kernel<<<dim3(BB), 256, 0, stream>>>(x2, W3, b3, (float*)d_out);
}